// Round 1
// baseline (344.171 us; speedup 1.0000x reference)
//
#include <hip/hip_runtime.h>
#include <cmath>

typedef unsigned short u16;
typedef unsigned int   u32;
typedef __attribute__((ext_vector_type(8))) short bf16x8;  // 8 bf16 in 4 VGPRs
typedef __attribute__((ext_vector_type(4))) float f32x4;   // MFMA accumulator

#define DEV __device__ __forceinline__
#define MFMA(a,b,c) __builtin_amdgcn_mfma_f32_16x16x32_bf16((a),(b),(c),0,0,0)

// ---- bf16 helpers (RNE) ----
DEV u16 f2bf(float x){ union{float f;u32 u;} v; v.f=x; u32 r=v.u+0x7FFFu+((v.u>>16)&1u); return (u16)(r>>16); }
DEV float bf2f(u16 h){ union{u32 u;float f;} v; v.u=((u32)h)<<16; return v.f; }

// ============================================================================
// prep kernels
// ============================================================================

// in fp32 [R][C] -> hi bf16 [C][R] (+ optional lo = bf16(x - hi))
__global__ __launch_bounds__(256) void k_transpose(const float* __restrict__ in,
        u16* __restrict__ hi, u16* __restrict__ lo, int R, int C){
    __shared__ float t[32][33];
    const int r0 = blockIdx.y*32, c0 = blockIdx.x*32;
    const int lr = threadIdx.x>>3, lc = (threadIdx.x&7)*4;
    float4 v = *(const float4*)(in + (size_t)(r0+lr)*C + c0 + lc);
    t[lr][lc]=v.x; t[lr][lc+1]=v.y; t[lr][lc+2]=v.z; t[lr][lc+3]=v.w;
    __syncthreads();
    float vals[4]; u16 h[4];
    #pragma unroll
    for(int j=0;j<4;++j){ vals[j]=t[lc+j][lr]; h[j]=f2bf(vals[j]); }
    ushort4 o; o.x=h[0]; o.y=h[1]; o.z=h[2]; o.w=h[3];
    *(ushort4*)(hi + (size_t)(c0+lr)*R + r0+lc) = o;
    if (lo){
        ushort4 q; q.x=f2bf(vals[0]-bf2f(h[0])); q.y=f2bf(vals[1]-bf2f(h[1]));
        q.z=f2bf(vals[2]-bf2f(h[2])); q.w=f2bf(vals[3]-bf2f(h[3]));
        *(ushort4*)(lo + (size_t)(c0+lr)*R + r0+lc) = q;
    }
}

// proj [64 d][256 m] fp32 -> packed B-fragments hi/lo:
// pPh[((nt*2+ks)*64 + lane)*8 + e] = bf16(proj[32*ks+8*(lane/16)+e][16*nt+lane%16])
__global__ __launch_bounds__(256) void k_pack_proj(const float* __restrict__ proj,
        u16* __restrict__ ph, u16* __restrict__ pl){
    int idx = blockIdx.x*256 + threadIdx.x;       // 0..16383
    int e = idx&7, l = (idx>>3)&63, f = idx>>9;   // f = nt*2+ks
    int nt = f>>1, ks = f&1;
    int d = 32*ks + 8*(l>>4) + e;
    int m = 16*nt + (l&15);
    float x = proj[d*256 + m];
    u16 h = f2bf(x);
    ph[idx] = h; pl[idx] = f2bf(x - bf2f(h));
}

__global__ __launch_bounds__(256) void k_convertX(const float* __restrict__ X, u16* __restrict__ Xb){
    size_t i = ((size_t)blockIdx.x*256 + threadIdx.x)*4;
    float4 v = *(const float4*)(X+i);
    ushort4 o; o.x=f2bf(v.x); o.y=f2bf(v.y); o.z=f2bf(v.z); o.w=f2bf(v.w);
    *(ushort4*)(Xb+i) = o;
}

// ============================================================================
// k_qkv: C = X @ {Wq,Wk,Wv}, BM=128 BN=128 BK=32, 4 waves.
// wsel<2: +bias, per-head (64-col) L2-normalize, store fp32 Qn/Kn [B*S][1024].
// wsel==2: +bias, store bf16 V transposed per head: VT[(b*16+h)*64+d][4096 s].
// grid (64, 24): y/8 = wsel, y%8 = 128-col block.
// ============================================================================
__global__ __launch_bounds__(256) void k_qkv(const u16* __restrict__ Xb, const u16* __restrict__ WT,
        const float* __restrict__ bq, const float* __restrict__ bk, const float* __restrict__ bv,
        float* __restrict__ Qn, float* __restrict__ Kn, u16* __restrict__ VT){
    __shared__ u16 As[128][40];   // [row s][k] pad->40 elems
    __shared__ u16 Bs[128][40];   // [col n][k]
    const int bx = blockIdx.x, y = blockIdx.y;
    const int wsel = y>>3, cb = y&7;
    const int tid = threadIdx.x, wv = tid>>6, l = tid&63, g = l>>4, c = l&15;
    const u16* Ap = Xb + (size_t)bx*128*1024;
    const u16* Bp = WT + (size_t)wsel*1048576 + (size_t)cb*128*1024;
    const int lr = tid>>1, lk = (tid&1)*16;
    f32x4 acc[2][8];
    #pragma unroll
    for(int mt=0;mt<2;++mt) for(int nt=0;nt<8;++nt) acc[mt][nt] = f32x4{0.f,0.f,0.f,0.f};
    for(int k0=0;k0<1024;k0+=32){
        const u16* pa = Ap + lr*1024 + k0 + lk;
        uint4 a0 = *(const uint4*)pa, a1 = *(const uint4*)(pa+8);
        const u16* pb = Bp + lr*1024 + k0 + lk;
        uint4 b0 = *(const uint4*)pb, b1 = *(const uint4*)(pb+8);
        __syncthreads();
        *(uint4*)&As[lr][lk] = a0; *(uint4*)&As[lr][lk+8] = a1;
        *(uint4*)&Bs[lr][lk] = b0; *(uint4*)&Bs[lr][lk+8] = b1;
        __syncthreads();
        bf16x8 af[2], bfr[8];
        #pragma unroll
        for(int mt=0;mt<2;++mt) af[mt] = *(const bf16x8*)&As[32*wv+16*mt+c][8*g];
        #pragma unroll
        for(int nt=0;nt<8;++nt) bfr[nt] = *(const bf16x8*)&Bs[16*nt+c][8*g];
        #pragma unroll
        for(int mt=0;mt<2;++mt)
            #pragma unroll
            for(int nt=0;nt<8;++nt)
                acc[mt][nt] = MFMA(af[mt], bfr[nt], acc[mt][nt]);
    }
    const int n0 = cb*128;
    const int b = bx>>5;
    const int sl0 = (bx&31)*128;
    if (wsel < 2){
        float* Out = wsel ? Kn : Qn;
        const float* bias = wsel ? bk : bq;
        float bb[8];
        #pragma unroll
        for(int nt=0;nt<8;++nt) bb[nt] = bias[n0+16*nt+c];
        #pragma unroll
        for(int mt=0;mt<2;++mt){
            #pragma unroll
            for(int nt=0;nt<8;++nt)
                #pragma unroll
                for(int r=0;r<4;++r) acc[mt][nt][r] += bb[nt];
            // per-head norm: head group hg covers nt 4hg..4hg+3 (64 cols with the 16-lane shfl)
            #pragma unroll
            for(int hg=0;hg<2;++hg)
                #pragma unroll
                for(int r=0;r<4;++r){
                    float ss = 0.f;
                    #pragma unroll
                    for(int q=0;q<4;++q){ float vv = acc[mt][4*hg+q][r]; ss += vv*vv; }
                    ss += __shfl_xor(ss,1); ss += __shfl_xor(ss,2);
                    ss += __shfl_xor(ss,4); ss += __shfl_xor(ss,8);
                    float sc = 1.f/(sqrtf(ss)+1e-6f);
                    #pragma unroll
                    for(int q=0;q<4;++q) acc[mt][4*hg+q][r] *= sc;
                }
            const int srow = bx*128 + 32*wv + 16*mt + 4*g;
            #pragma unroll
            for(int nt=0;nt<8;++nt)
                #pragma unroll
                for(int r=0;r<4;++r)
                    Out[(size_t)(srow+r)*1024 + n0 + 16*nt + c] = acc[mt][nt][r];
        }
    } else {
        float bb[8];
        #pragma unroll
        for(int nt=0;nt<8;++nt) bb[nt] = bv[n0+16*nt+c];
        #pragma unroll
        for(int mt=0;mt<2;++mt)
            #pragma unroll
            for(int nt=0;nt<8;++nt){
                const int ncol = n0 + 16*nt + c;
                const int h = ncol>>6, d = ncol&63;
                const int s0m = sl0 + 32*wv + 16*mt + 4*g;
                ushort4 o;
                o.x = f2bf(acc[mt][nt][0]+bb[nt]); o.y = f2bf(acc[mt][nt][1]+bb[nt]);
                o.z = f2bf(acc[mt][nt][2]+bb[nt]); o.w = f2bf(acc[mt][nt][3]+bb[nt]);
                *(ushort4*)(VT + ((size_t)(b*16+h)*64 + d)*4096 + s0m) = o;
            }
    }
}

// ============================================================================
// k_kv: per (chunk, b*16+h): KV[m,d] = sum_s phiK[s,m] V[s,d]; Z[m] = sum_s phiK[s,m]
// phiK computed on the fly from Kn (hi/lo split x proj hi/lo, 3 MFMA passes),
// staged transposed in LDS [m][s]. Split-K over 8 chunks of 512 s -> partials.
// grid (8, 32), 4 waves; wave w owns m rows 64w..64w+63.
// ============================================================================
__global__ __launch_bounds__(256) void k_kv(const float* __restrict__ Kn,
        const u16* __restrict__ pPh, const u16* __restrict__ pPl,
        const float* __restrict__ mask, const u16* __restrict__ VT,
        float* __restrict__ KVpart, float* __restrict__ Zpart){
    __shared__ u16 phiT[256][72];     // [m][s], pad 72
    __shared__ u16 Vs[64][72];        // [d][s]
    __shared__ float zbuf[4][256];
    const int chunk = blockIdx.x, bh = blockIdx.y;
    const int b = bh>>4, h = bh&15;
    const int tid = threadIdx.x, wv = tid>>6, l = tid&63, g = l>>4, c = l&15;
    f32x4 kv[4][4];
    #pragma unroll
    for(int mt=0;mt<4;++mt) for(int dt=0;dt<4;++dt) kv[mt][dt] = f32x4{0.f,0.f,0.f,0.f};
    float zacc[16];
    #pragma unroll
    for(int nt=0;nt<16;++nt) zacc[nt]=0.f;
    const int vd = tid>>2, vs = (tid&3)*16;
    for(int t=0;t<8;++t){
        const int s0 = chunk*512 + t*64;
        __syncthreads();                       // protect prev-iter LDS reads
        { // stage V tile [64 d][64 s]
            const u16* pv = VT + ((size_t)bh*64 + vd)*4096 + s0 + vs;
            uint4 v0 = *(const uint4*)pv, v1 = *(const uint4*)(pv+8);
            *(uint4*)&Vs[vd][vs] = v0; *(uint4*)&Vs[vd][vs+8] = v1;
        }
        // phase A: u = Kn_head @ proj  (wave w -> s rows 16w..16w+15)
        f32x4 ph[16];
        #pragma unroll
        for(int nt=0;nt<16;++nt) ph[nt] = f32x4{0.f,0.f,0.f,0.f};
        #pragma unroll
        for(int ks=0;ks<2;++ks){
            const int srow = s0 + 16*wv + c;
            const float* ap = Kn + (size_t)(b*4096+srow)*1024 + h*64 + 32*ks + 8*g;
            float4 x0 = *(const float4*)ap, x1 = *(const float4*)(ap+4);
            float xv[8] = {x0.x,x0.y,x0.z,x0.w,x1.x,x1.y,x1.z,x1.w};
            bf16x8 ah, al;
            #pragma unroll
            for(int e=0;e<8;++e){ u16 hh=f2bf(xv[e]); ah[e]=(short)hh; al[e]=(short)f2bf(xv[e]-bf2f(hh)); }
            #pragma unroll
            for(int nt=0;nt<16;++nt){
                bf16x8 bh8 = *(const bf16x8*)(pPh + ((size_t)(nt*2+ks)*64 + l)*8);
                bf16x8 bl8 = *(const bf16x8*)(pPl + ((size_t)(nt*2+ks)*64 + l)*8);
                ph[nt] = MFMA(ah, bh8, ph[nt]);
                ph[nt] = MFMA(ah, bl8, ph[nt]);
                ph[nt] = MFMA(al, bh8, ph[nt]);
            }
        }
        float mk[4];
        #pragma unroll
        for(int r=0;r<4;++r) mk[r] = mask[b*4096 + s0 + 16*wv + 4*g + r];
        #pragma unroll
        for(int nt=0;nt<16;++nt){
            float zs = 0.f;
            #pragma unroll
            for(int r=0;r<4;++r){
                float phv = expf(ph[nt][r]-0.5f)*0.0625f*mk[r];
                phiT[c+16*nt][16*wv+4*g+r] = f2bf(phv);
                zs += phv;
            }
            zacc[nt] += zs;
        }
        __syncthreads();
        // phase B: KV += phiT(A, rows m) x Vs(B, cols d)
        #pragma unroll
        for(int ks=0;ks<2;++ks){
            bf16x8 afr[4], bfr[4];
            #pragma unroll
            for(int mt=0;mt<4;++mt) afr[mt] = *(const bf16x8*)&phiT[64*wv+16*mt+c][32*ks+8*g];
            #pragma unroll
            for(int dt=0;dt<4;++dt) bfr[dt] = *(const bf16x8*)&Vs[16*dt+c][32*ks+8*g];
            #pragma unroll
            for(int mt=0;mt<4;++mt)
                #pragma unroll
                for(int dt=0;dt<4;++dt)
                    kv[mt][dt] = MFMA(afr[mt], bfr[dt], kv[mt][dt]);
        }
    }
    // Z partial
    #pragma unroll
    for(int nt=0;nt<16;++nt){
        float z = zacc[nt];
        z += __shfl_xor(z,16); z += __shfl_xor(z,32);
        if (g==0) zbuf[wv][c+16*nt] = z;
    }
    __syncthreads();
    {
        float z = zbuf[0][tid]+zbuf[1][tid]+zbuf[2][tid]+zbuf[3][tid];
        Zpart[((size_t)bh*8+chunk)*256 + tid] = z;
    }
    float* kout = KVpart + ((size_t)bh*8+chunk)*16384;   // [256 m][64 d]
    #pragma unroll
    for(int mt=0;mt<4;++mt)
        #pragma unroll
        for(int dt=0;dt<4;++dt)
            #pragma unroll
            for(int r=0;r<4;++r)
                kout[(64*wv+16*mt+4*g+r)*64 + 16*dt + c] = kv[mt][dt][r];
}

// reduce split-K partials -> KVT[d][m] bf16, Z fp32. grid (32)
__global__ __launch_bounds__(256) void k_kvreduce(const float* __restrict__ KVpart,
        const float* __restrict__ Zpart, u16* __restrict__ KVT, float* __restrict__ Z){
    const int bh = blockIdx.x, tid = threadIdx.x;
    float a[64];
    #pragma unroll
    for(int k=0;k<64;++k) a[k]=0.f;
    for(int ch=0; ch<8; ++ch){
        const float* p = KVpart + ((size_t)bh*8+ch)*16384;
        #pragma unroll
        for(int k=0;k<64;++k) a[k] += p[k*256 + tid];
    }
    #pragma unroll
    for(int k=0;k<64;++k){
        int i = k*256 + tid, m = i>>6, d = i&63;
        KVT[((size_t)bh*64 + d)*256 + m] = f2bf(a[k]);
    }
    float z = 0.f;
    for(int ch=0; ch<8; ++ch) z += Zpart[((size_t)bh*8+ch)*256 + tid];
    Z[bh*256 + tid] = z;
}

// ============================================================================
// k_attn: per (s-tile 64, b*16+h): phiQ on the fly, den = phiQ.Z (fp32, shfl-
// reduced), num = phiQ @ KV, attn = 8*num/den -> fp32 [B*S][1024].
// grid (64, 32), 4 waves; wave w -> s rows 16w..16w+15 in both phases.
// ============================================================================
__global__ __launch_bounds__(256) void k_attn(const float* __restrict__ Qn,
        const u16* __restrict__ pPh, const u16* __restrict__ pPl,
        const u16* __restrict__ KVT, const float* __restrict__ Z, float* __restrict__ attn){
    __shared__ u16 phi[64][264];      // [s][m], pad 264
    __shared__ float Zs[256];
    const int st = blockIdx.x, bh = blockIdx.y;
    const int b = bh>>4, h = bh&15;
    const int tid = threadIdx.x, wv = tid>>6, l = tid&63, g = l>>4, c = l&15;
    Zs[tid] = Z[bh*256 + tid];
    const int s0 = st*64;
    f32x4 ph[16];
    #pragma unroll
    for(int nt=0;nt<16;++nt) ph[nt] = f32x4{0.f,0.f,0.f,0.f};
    #pragma unroll
    for(int ks=0;ks<2;++ks){
        const int srow = s0 + 16*wv + c;
        const float* ap = Qn + (size_t)(b*4096+srow)*1024 + h*64 + 32*ks + 8*g;
        float4 x0 = *(const float4*)ap, x1 = *(const float4*)(ap+4);
        float xv[8] = {x0.x,x0.y,x0.z,x0.w,x1.x,x1.y,x1.z,x1.w};
        bf16x8 ah, al;
        #pragma unroll
        for(int e=0;e<8;++e){ u16 hh=f2bf(xv[e]); ah[e]=(short)hh; al[e]=(short)f2bf(xv[e]-bf2f(hh)); }
        #pragma unroll
        for(int nt=0;nt<16;++nt){
            bf16x8 bh8 = *(const bf16x8*)(pPh + ((size_t)(nt*2+ks)*64 + l)*8);
            bf16x8 bl8 = *(const bf16x8*)(pPl + ((size_t)(nt*2+ks)*64 + l)*8);
            ph[nt] = MFMA(ah, bh8, ph[nt]);
            ph[nt] = MFMA(ah, bl8, ph[nt]);
            ph[nt] = MFMA(al, bh8, ph[nt]);
        }
    }
    __syncthreads();                  // Zs visible
    float den[4] = {0.f,0.f,0.f,0.f};
    #pragma unroll
    for(int nt=0;nt<16;++nt){
        float zv = Zs[c+16*nt];
        #pragma unroll
        for(int r=0;r<4;++r){
            float phv = expf(ph[nt][r]-0.5f)*0.0625f;
            den[r] += phv*zv;
            phi[16*wv+4*g+r][c+16*nt] = f2bf(phv);
        }
    }
    #pragma unroll
    for(int r=0;r<4;++r){
        den[r] += __shfl_xor(den[r],1); den[r] += __shfl_xor(den[r],2);
        den[r] += __shfl_xor(den[r],4); den[r] += __shfl_xor(den[r],8);
        den[r] += 1e-6f;
    }
    __syncthreads();                  // phi written
    f32x4 nm[4];
    #pragma unroll
    for(int dt=0;dt<4;++dt) nm[dt] = f32x4{0.f,0.f,0.f,0.f};
    #pragma unroll
    for(int j=0;j<8;++j){
        bf16x8 af = *(const bf16x8*)&phi[16*wv+c][32*j+8*g];
        #pragma unroll
        for(int dt=0;dt<4;++dt){
            bf16x8 bfr = *(const bf16x8*)(KVT + ((size_t)bh*64 + 16*dt + c)*256 + 32*j + 8*g);
            nm[dt] = MFMA(af, bfr, nm[dt]);
        }
    }
    #pragma unroll
    for(int dt=0;dt<4;++dt)
        #pragma unroll
        for(int r=0;r<4;++r){
            const int srow = s0 + 16*wv + 4*g + r;
            attn[(size_t)(b*4096+srow)*1024 + h*64 + 16*dt + c] = nm[dt][r]*8.f/den[r];
        }
}

// ============================================================================
// k_out: out = attn @ Wf + bf, with attn and Wf split hi/lo (3 MFMA passes).
// BM=128 BN=128 BK=32, grid (64, 8). fp32 output.
// ============================================================================
__global__ __launch_bounds__(256) void k_out(const float* __restrict__ attn,
        const u16* __restrict__ Wh, const u16* __restrict__ Wl,
        const float* __restrict__ bfb, float* __restrict__ out){
    __shared__ u16 Ah[128][40], Al[128][40], Bh[128][40], Bl[128][40];
    const int bx = blockIdx.x, by = blockIdx.y;
    const int tid = threadIdx.x, wv = tid>>6, l = tid&63, g = l>>4, c = l&15;
    const int lr = tid>>1, lk = (tid&1)*16;
    f32x4 acc[2][8];
    #pragma unroll
    for(int mt=0;mt<2;++mt) for(int nt=0;nt<8;++nt) acc[mt][nt] = f32x4{0.f,0.f,0.f,0.f};
    for(int k0=0;k0<1024;k0+=32){
        const float* pa = attn + (size_t)(bx*128+lr)*1024 + k0 + lk;
        float4 a0=*(const float4*)pa, a1=*(const float4*)(pa+4), a2=*(const float4*)(pa+8), a3=*(const float4*)(pa+12);
        float av[16] = {a0.x,a0.y,a0.z,a0.w,a1.x,a1.y,a1.z,a1.w,a2.x,a2.y,a2.z,a2.w,a3.x,a3.y,a3.z,a3.w};
        u16 hv[16], lv[16];
        #pragma unroll
        for(int i=0;i<16;++i){ hv[i]=f2bf(av[i]); lv[i]=f2bf(av[i]-bf2f(hv[i])); }
        const u16* pb = Wh + (size_t)(by*128+lr)*1024 + k0 + lk;
        uint4 wb0 = *(const uint4*)pb, wb1 = *(const uint4*)(pb+8);
        const u16* pc = Wl + (size_t)(by*128+lr)*1024 + k0 + lk;
        uint4 wc0 = *(const uint4*)pc, wc1 = *(const uint4*)(pc+8);
        __syncthreads();
        #pragma unroll
        for(int half=0; half<2; ++half){
            u32 pk[4], ql[4];
            #pragma unroll
            for(int i=0;i<4;++i){
                pk[i] = (u32)hv[half*8+2*i] | ((u32)hv[half*8+2*i+1]<<16);
                ql[i] = (u32)lv[half*8+2*i] | ((u32)lv[half*8+2*i+1]<<16);
            }
            *(uint4*)&Ah[lr][lk+8*half] = make_uint4(pk[0],pk[1],pk[2],pk[3]);
            *(uint4*)&Al[lr][lk+8*half] = make_uint4(ql[0],ql[1],ql[2],ql[3]);
        }
        *(uint4*)&Bh[lr][lk] = wb0; *(uint4*)&Bh[lr][lk+8] = wb1;
        *(uint4*)&Bl[lr][lk] = wc0; *(uint4*)&Bl[lr][lk+8] = wc1;
        __syncthreads();
        bf16x8 ahf[2], alf[2];
        #pragma unroll
        for(int mt=0;mt<2;++mt){
            ahf[mt] = *(const bf16x8*)&Ah[32*wv+16*mt+c][8*g];
            alf[mt] = *(const bf16x8*)&Al[32*wv+16*mt+c][8*g];
        }
        #pragma unroll
        for(int nt=0;nt<8;++nt){
            bf16x8 bh8 = *(const bf16x8*)&Bh[16*nt+c][8*g];
            bf16x8 bl8 = *(const bf16x8*)&Bl[16*nt+c][8*g];
            #pragma unroll
            for(int mt=0;mt<2;++mt){
                acc[mt][nt] = MFMA(ahf[mt], bh8, acc[mt][nt]);
                acc[mt][nt] = MFMA(ahf[mt], bl8, acc[mt][nt]);
                acc[mt][nt] = MFMA(alf[mt], bh8, acc[mt][nt]);
            }
        }
    }
    #pragma unroll
    for(int mt=0;mt<2;++mt)
        #pragma unroll
        for(int nt=0;nt<8;++nt){
            const float bb = bfb[by*128+16*nt+c];
            #pragma unroll
            for(int r=0;r<4;++r)
                out[(size_t)(bx*128+32*wv+16*mt+4*g+r)*1024 + by*128+16*nt+c] = acc[mt][nt][r] + bb;
        }
}

// ============================================================================
extern "C" void kernel_launch(void* const* d_in, const int* in_sizes, int n_in,
                              void* d_out, int out_size, void* d_ws, size_t ws_size,
                              hipStream_t stream){
    (void)in_sizes; (void)n_in; (void)out_size;
    const float* X    = (const float*)d_in[0];
    const float* mask = (const float*)d_in[1];
    const float* Wq   = (const float*)d_in[2];
    const float* bq   = (const float*)d_in[3];
    const float* Wk   = (const float*)d_in[4];
    const float* bk   = (const float*)d_in[5];
    const float* Wv   = (const float*)d_in[6];
    const float* bv   = (const float*)d_in[7];
    const float* Wf   = (const float*)d_in[8];
    const float* bfb  = (const float*)d_in[9];
    const float* proj = (const float*)d_in[10];
    float* out = (float*)d_out;

    char* w = (char*)d_ws;
    size_t off = 0;
    auto alloc = [&](size_t n)->void*{ void* p = w + off; off = (off + n + 255) & ~(size_t)255; return p; };
    u16*   Xb     = (u16*)  alloc((size_t)8192*1024*2);   // X bf16
    u16*   WT     = (u16*)  alloc((size_t)3*1048576*2);   // Wq,Wk,Wv transposed [n][k]
    u16*   Wfh    = (u16*)  alloc((size_t)1048576*2);     // WfT hi
    u16*   Wfl    = (u16*)  alloc((size_t)1048576*2);     // WfT lo
    u16*   pPh    = (u16*)  alloc(16384*2);               // proj packed hi
    u16*   pPl    = (u16*)  alloc(16384*2);               // proj packed lo
    float* Qn     = (float*)alloc((size_t)8192*1024*4);   // normalized Q fp32
    float* Kn     = (float*)alloc((size_t)8192*1024*4);   // normalized K fp32
    u16*   VT     = (u16*)  alloc((size_t)32*64*4096*2);  // V^T per head bf16
    float* KVpart = (float*)alloc((size_t)32*8*16384*4);  // split-K KV partials
    float* Zpart  = (float*)alloc((size_t)32*8*256*4);
    u16*   KVT    = (u16*)  alloc((size_t)32*64*256*2);   // KV^T [d][m] bf16
    float* Zr     = (float*)alloc((size_t)32*256*4);
    float* attnB  = (float*)alloc((size_t)8192*1024*4);   // attn fp32
    if (off > ws_size) return;  // ws too small: fail cleanly (output stays zero)

    k_transpose<<<dim3(32,32), 256, 0, stream>>>(Wq, WT,           (u16*)nullptr, 1024, 1024);
    k_transpose<<<dim3(32,32), 256, 0, stream>>>(Wk, WT+1048576,   (u16*)nullptr, 1024, 1024);
    k_transpose<<<dim3(32,32), 256, 0, stream>>>(Wv, WT+2097152,   (u16*)nullptr, 1024, 1024);
    k_transpose<<<dim3(32,32), 256, 0, stream>>>(Wf, Wfh, Wfl, 1024, 1024);
    k_pack_proj<<<dim3(64), 256, 0, stream>>>(proj, pPh, pPl);
    k_convertX<<<dim3(8192), 256, 0, stream>>>(X, Xb);
    k_qkv<<<dim3(64,24), 256, 0, stream>>>(Xb, WT, bq, bk, bv, Qn, Kn, VT);
    k_kv<<<dim3(8,32), 256, 0, stream>>>(Kn, pPh, pPl, mask, VT, KVpart, Zpart);
    k_kvreduce<<<dim3(32), 256, 0, stream>>>(KVpart, Zpart, KVT, Zr);
    k_attn<<<dim3(64,32), 256, 0, stream>>>(Qn, pPh, pPl, KVT, Zr, attnB);
    k_out<<<dim3(64,8), 256, 0, stream>>>(attnB, Wfh, Wfl, bfb, out);
}